// Round 29
// baseline (180.579 us; speedup 1.0000x reference)
//
#include <hip/hip_runtime.h>
#include <hip/hip_bf16.h>
#include <math.h>

// Problem constants
#define BB 2
#define SS 2048
#define DD 2048
#define HH 16
#define GG 4
#define HDIM 128
#define DKV (GG * HDIM)      // 512
#define MS (BB * SS)         // 4096 rows
#define QKVS 3072            // fused QKV row stride (2048 Q + 512 K + 512 V)

typedef __attribute__((ext_vector_type(8))) short bf16x8;
typedef __attribute__((ext_vector_type(4))) float f32x4;
typedef __attribute__((ext_vector_type(4))) unsigned int u32x4;

#if __has_builtin(__builtin_amdgcn_exp2f)
#define EXP2F __builtin_amdgcn_exp2f
#else
#define EXP2F exp2f
#endif

__device__ __forceinline__ ushort f2bf(float x) {
    __hip_bfloat16 b = __float2bfloat16(x);
    return *(ushort*)&b;
}
__device__ __forceinline__ float bf2f(ushort u) {
    __hip_bfloat16 b;
    *(ushort*)&b = u;
    return __bfloat162float(b);
}

#define GLOAD_LDS(src, dst)                                                        \
    __builtin_amdgcn_global_load_lds(                                              \
        (const __attribute__((address_space(1))) unsigned int*)(src),              \
        (__attribute__((address_space(3))) unsigned int*)(dst), 16, 0, 0)

#define WAITV(n) asm volatile("s_waitcnt vmcnt(" #n ")" ::: "memory")

// ---- merged prep: z=0 Wq, z=1 Wk, z=2 Wv -> WqkvT; z=3 Wo -> WoT; z=4 x-cast ----
__global__ __launch_bounds__(256) void prep4(const float* __restrict__ x,
                                             const float* __restrict__ Wq,
                                             const float* __restrict__ Wk,
                                             const float* __restrict__ Wv,
                                             const float* __restrict__ Wo,
                                             ushort* __restrict__ xh,
                                             ushort* __restrict__ WqkvT,
                                             ushort* __restrict__ WoT) {
    __shared__ ushort tile[32][33];
    const int z = blockIdx.z;
    if (z == 4) {
        int idx = (blockIdx.y * 64 + blockIdx.x) * 256 + threadIdx.x;
        const float4* p = (const float4*)x + (size_t)idx * 2;
        float4 a = p[0], b = p[1];
        float v[8] = {a.x, a.y, a.z, a.w, b.x, b.y, b.z, b.w};
        ushort r[8];
#pragma unroll
        for (int j = 0; j < 8; ++j) r[j] = f2bf(v[j]);
        *((u32x4*)xh + idx) = *(u32x4*)r;
        return;
    }
    if ((z == 1 || z == 2) && blockIdx.x >= DKV / 32) return;
    const float* W = (z == 0) ? Wq : (z == 1) ? Wk : (z == 2) ? Wv : Wo;
    ushort* WT = (z == 3) ? WoT
                          : WqkvT + ((z == 0) ? (size_t)0
                                              : (z == 1) ? (size_t)DD * DD
                                                         : (size_t)(DD + DKV) * DD);
    const int N = (z == 1 || z == 2) ? DKV : DD;
    const int tx = threadIdx.x & 31, ty = threadIdx.x >> 5;  // 32 x 8
    const int n0 = blockIdx.x * 32, k0 = blockIdx.y * 32;
#pragma unroll
    for (int i = 0; i < 4; ++i)
        tile[ty + i * 8][tx] = f2bf(W[(size_t)(k0 + ty + i * 8) * N + n0 + tx]);
    __syncthreads();
#pragma unroll
    for (int i = 0; i < 4; ++i)
        WT[(size_t)(n0 + ty + i * 8) * DD + k0 + tx] = tile[tx][ty + i * 8];
}

// -------- QKV GEMM + fused RoPE epilogue + fused V-transpose epilogue ---------
// BM=BN=128, BK=32, ring-3, 3/CU. n-frag remap {wc*32, +16, +64, +80} so
// acc[m][n]/acc[m][n+2] hold the rope (i, i+64) pair in-register.
// bn < 2560 (Q,K): rope in epilogue, write QKV. bn >= 2560 (V): transpose +
// tau-permute through reused LDS straight into VT (QKV V-region never written).
__global__ __launch_bounds__(512) void gemm_qkv(const ushort* __restrict__ A,
                                                const ushort* __restrict__ BT,
                                                ushort* __restrict__ C,
                                                ushort* __restrict__ VT,
                                                int M, int N, int K) {
    constexpr int ABUF = 128 * 32;
    constexpr int BBUF = 128 * 32;
    constexpr int ROWS = 32;   // rows per wave (4 M-waves)
    constexpr int MFR = 2;     // A fragments per wave
    __shared__ ushort As[3 * ABUF + 3 * BBUF];  // 48 KB, also reused as vt tile
    ushort* Bs = As + 3 * ABUF;
    ushort* vt = As;           // V-epilogue tile [128][140], 17920 <= 24576 ush

    const int t = threadIdx.x;
    const int w = t >> 6, l = t & 63;
    const int lm = l & 15, lw = l >> 4;
    const int wr = w >> 1, wc = w & 1;
    const int nx = gridDim.x;
    const int bid = blockIdx.y * nx + blockIdx.x;
    const int cpx = (nx * gridDim.y) >> 3;
    const int swb = (bid & 7) * cpx + (bid >> 3);
    const int bm = (swb / nx) * 128, bn = (swb % nx) * 128;

    const int NT = K >> 5;
    const int swzc = (lw ^ ((lm >> 1) & 3)) * 8;

    const int ar0 = t >> 2, ac0 = (t & 3) ^ ((ar0 >> 1) & 3);
    const ushort* a0 = A + (size_t)(bm + ar0) * K + ac0 * 8;
    const ushort* b0 = BT + (size_t)(bn + ar0) * K + ac0 * 8;

    auto STAGE = [&](int slot) {
        GLOAD_LDS(a0, &As[slot * ABUF + t * 8]);
        a0 += 32;
        GLOAD_LDS(b0, &Bs[slot * BBUF + t * 8]);
        b0 += 32;
    };

    // remapped n-fragment columns (rope pairs: n and n+2)
    const int ncol[4] = {wc * 32, wc * 32 + 16, wc * 32 + 64, wc * 32 + 80};

    f32x4 acc[MFR][4];
#pragma unroll
    for (int m = 0; m < MFR; ++m)
#pragma unroll
        for (int n = 0; n < 4; ++n) acc[m][n] = (f32x4){0.f, 0.f, 0.f, 0.f};

    STAGE(0);
    STAGE(1);
    int cs = 0, ps = 2;

#pragma unroll 1
    for (int kt = 0; kt < NT; ++kt) {
        if (kt + 1 < NT) {
            WAITV(2);
        } else {
            WAITV(0);
        }
        __builtin_amdgcn_s_barrier();
        if (kt + 2 < NT) STAGE(ps);

        const ushort* Ab = &As[cs * ABUF];
        const ushort* Bb = &Bs[cs * BBUF];
        bf16x8 bfr[4], af[MFR];
#pragma unroll
        for (int n = 0; n < 4; ++n)
            bfr[n] = *(const bf16x8*)&Bb[(ncol[n] + lm) * 32 + swzc];
#pragma unroll
        for (int i = 0; i < MFR; ++i)
            af[i] = *(const bf16x8*)&Ab[(wr * ROWS + i * 16 + lm) * 32 + swzc];
        __builtin_amdgcn_s_setprio(1);
#pragma unroll
        for (int i = 0; i < MFR; ++i)
#pragma unroll
            for (int n = 0; n < 4; ++n)
                acc[i][n] = __builtin_amdgcn_mfma_f32_16x16x32_bf16(af[i], bfr[n], acc[i][n], 0, 0, 0);
        __builtin_amdgcn_s_setprio(0);

        cs = (cs == 2) ? 0 : cs + 1;
        ps = (ps == 2) ? 0 : ps + 1;
    }

    // epilogue: C/D layout col=lm(+ncol), row=lw*4+reg (verified)
    if (bn < 2560) {
        // Q/K head block: apply rope to fp32 acc (pairs n, n+2), write bf16
#pragma unroll
        for (int n = 0; n < 2; ++n) {
            const int i = wc * 32 + n * 16 + lm;  // position within head, [0,64)
            const float inv = exp2f((float)i * -0.2076205059304601f);  // 10000^(-2i/128)
#pragma unroll
            for (int m = 0; m < MFR; ++m)
#pragma unroll
                for (int r = 0; r < 4; ++r) {
                    int row = bm + wr * ROWS + m * 16 + lw * 4 + r;
                    float ang = (float)(row & (SS - 1)) * inv;
                    float c, sn;
                    __sincosf(ang, &sn, &c);
                    float x1 = acc[m][n][r], x2 = acc[m][n + 2][r];
                    size_t base = (size_t)row * QKVS + bn + ncol[n] + lm;
                    C[base] = f2bf(x1 * c - x2 * sn);
                    C[base + 64] = f2bf(x2 * c + x1 * sn);
                }
        }
    } else {
        // V block: transpose + tau-permute straight to VT via reused LDS.
        // drain LDS pipe + barrier before overwriting ring buffers (other
        // waves may still have last-tile ds_reads in flight).
        asm volatile("s_waitcnt lgkmcnt(0)" ::: "memory");
        __builtin_amdgcn_s_barrier();
        // stage acc -> vt[row=kv_local][col=dkv_local], pad 140 (write conflict-free)
#pragma unroll
        for (int m = 0; m < MFR; ++m)
#pragma unroll
            for (int n = 0; n < 4; ++n)
#pragma unroll
                for (int r = 0; r < 4; ++r) {
                    int rl = wr * ROWS + m * 16 + lw * 4 + r;
                    vt[rl * 140 + ncol[n] + lm] = f2bf(acc[m][n][r]);
                }
        __syncthreads();
        // read inverse-tau (pos = 32a+8w'+4m'+r <-> kv = 32a+16m'+4w'+r),
        // write coalesced 16B chunks: VT[dkv][k0g + pos]
        const int bb = bm >> 11;          // batch
        const int k0g = bm & 2047;        // kv base within batch
        const int d0 = bn - 2560;         // dkv base
#pragma unroll
        for (int it = 0; it < 4; ++it) {
            int j = it * 4096 + t * 8;
            int dkv = j >> 7;
            int poff = j & 127;
            int kv8 = (poff & 96) + ((poff >> 3) & 3) * 4;  // 32a + 4w'
            ushort vals[8];
#pragma unroll
            for (int r = 0; r < 4; ++r) {
                vals[r] = vt[(kv8 + r) * 140 + dkv];          // m'=0
                vals[4 + r] = vt[(kv8 + 16 + r) * 140 + dkv];  // m'=1
            }
            *(u32x4*)&VT[((size_t)bb * DKV + d0 + dkv) * SS + k0g + poff] = *(u32x4*)vals;
        }
    }
}

// ---------------- bf16 MFMA GEMM v4 (Wo): BM=BN=128, BK=64, dbuf, 2/CU ---------
template <bool OUT_BF16>
__global__ __launch_bounds__(512) void gemm64(const ushort* __restrict__ A,
                                              const ushort* __restrict__ BT,
                                              void* __restrict__ Cout,
                                              int M, int N, int K) {
    __shared__ ushort As[2][128 * 64];  // 32 KB
    __shared__ ushort Bs[2][128 * 64];  // 32 KB
    const int t = threadIdx.x;
    const int w = t >> 6, l = t & 63;
    const int lm = l & 15, lw = l >> 4;
    const int wr = w >> 1, wc = w & 1;  // 4 M-waves x 2 N-waves
    const int nx = gridDim.x;
    const int bid = blockIdx.y * nx + blockIdx.x;
    const int cpx = (nx * gridDim.y) >> 3;
    const int swb = (bid & 7) * cpx + (bid >> 3);
    const int bm = (swb / nx) * 128, bn = (swb % nx) * 128;
    const int NT = K >> 6;

    const int rowc = t >> 3, cc = t & 7;
    const int xb = (cc ^ (rowc & 7)) * 8;  // (rowc+64)&7 == rowc&7
    const ushort* a0 = A + (size_t)(bm + rowc) * K + xb;
    const ushort* a1 = A + (size_t)(bm + rowc + 64) * K + xb;
    const ushort* b0 = BT + (size_t)(bn + rowc) * K + xb;
    const ushort* b1 = BT + (size_t)(bn + rowc + 64) * K + xb;
    const int d0 = t * 8, d1 = (t + 512) * 8;

    auto STAGE = [&](int s) {
        GLOAD_LDS(a0, &As[s][d0]);
        a0 += 64;
        GLOAD_LDS(a1, &As[s][d1]);
        a1 += 64;
        GLOAD_LDS(b0, &Bs[s][d0]);
        b0 += 64;
        GLOAD_LDS(b1, &Bs[s][d1]);
        b1 += 64;
    };

    f32x4 acc[2][4];
#pragma unroll
    for (int m = 0; m < 2; ++m)
#pragma unroll
        for (int n = 0; n < 4; ++n) acc[m][n] = (f32x4){0.f, 0.f, 0.f, 0.f};

    STAGE(0);
    WAITV(0);
    __builtin_amdgcn_s_barrier();

    int buf = 0;
#pragma unroll 1
    for (int kt = 0; kt < NT; ++kt) {
        const bool more = (kt + 1 < NT);
        if (more) STAGE(buf ^ 1);

        bf16x8 af[2][2], bfr[4][2];
#pragma unroll
        for (int ks = 0; ks < 2; ++ks) {
            const int col = (((ks << 2) | lw) ^ (lm & 7)) * 8;
#pragma unroll
            for (int n = 0; n < 4; ++n)
                bfr[n][ks] = *(const bf16x8*)&Bs[buf][(wc * 64 + n * 16 + lm) * 64 + col];
#pragma unroll
            for (int i = 0; i < 2; ++i)
                af[i][ks] = *(const bf16x8*)&As[buf][(wr * 32 + i * 16 + lm) * 64 + col];
        }
        __builtin_amdgcn_s_setprio(1);
#pragma unroll
        for (int ks = 0; ks < 2; ++ks)
#pragma unroll
            for (int i = 0; i < 2; ++i)
#pragma unroll
                for (int n = 0; n < 4; ++n)
                    acc[i][n] = __builtin_amdgcn_mfma_f32_16x16x32_bf16(af[i][ks], bfr[n][ks], acc[i][n], 0, 0, 0);
        __builtin_amdgcn_s_setprio(0);

        if (more) {
            WAITV(0);
            __builtin_amdgcn_s_barrier();
        }
        buf ^= 1;
    }

#pragma unroll
    for (int m = 0; m < 2; ++m)
#pragma unroll
        for (int n = 0; n < 4; ++n)
#pragma unroll
            for (int r = 0; r < 4; ++r) {
                int row = bm + wr * 32 + m * 16 + lw * 4 + r;
                int col = bn + wc * 64 + n * 16 + lm;
                if (OUT_BF16)
                    ((ushort*)Cout)[(size_t)row * N + col] = f2bf(acc[m][n][r]);
                else
                    ((float*)Cout)[(size_t)row * N + col] = acc[m][n][r];
            }
}

// ---------------- MFMA flash attention v14: kv-tile 128 (round-17/23 verified) --
#define SCL 0.08838834764831845f          // 1/sqrt(128)
#define CEXP 0.1275296340545927f          // SCL * log2(e)
#define THRRAW 90.50966799187809f         // 8 / SCL

__global__ __launch_bounds__(512) void attn_mfma(const ushort* __restrict__ QKV,
                                                 const ushort* __restrict__ VT,
                                                 ushort* __restrict__ Ctx) {
    __shared__ ushort Ks[2][128 * 128];  // 64 KB
    __shared__ ushort Vs[2][128 * 128];  // 64 KB
    const int t = threadIdx.x;           // 0..511
    const int w = t >> 6;                // wave 0..7
    const int l = t & 63;
    const int lm = l & 15, lw = l >> 4;
    const int bid = blockIdx.x;
    const int g = bid & 3;
    const int b = (bid >> 2) & 1;
    const int within = bid >> 3;
    const int xq = within & 7;
    const int h = g * 4 + (within >> 3);
    const int swz = (lm & 7) << 3;

    const ushort* kbase = QKV + (size_t)(b * SS) * QKVS + 2048 + g * HDIM;
    const ushort* vbase = VT + ((size_t)b * DKV + g * HDIM) * SS;

    const short one_bf = (short)0x3F80;
    const bf16x8 ones = {one_bf, one_bf, one_bf, one_bf, one_bf, one_bf, one_bf, one_bf};

    int krr[4], koo[4];
#pragma unroll
    for (int it = 0; it < 4; ++it) {
        int c = t + it * 512;
        krr[it] = c >> 4;
        koo[it] = (c & 15) ^ (krr[it] & 7);
    }

#pragma unroll 1
    for (int phase = 0; phase < 2; ++phase) {
        const int qt = (phase == 0) ? xq : (15 - xq);
        const int q0 = qt * 128;
        const int qw = q0 + w * 16;
        const int q = qw + lm;
        const int ntiles = qt + 1;

        const ushort* ks[4];
        const ushort* vs[4];
#pragma unroll
        for (int it = 0; it < 4; ++it) {
            ks[it] = kbase + (size_t)krr[it] * QKVS + koo[it] * 8;
            vs[it] = vbase + (size_t)krr[it] * SS + koo[it] * 8;
        }

        bf16x8 qa[4];
        {
            const ushort* qp = QKV + (size_t)(b * SS + qw + lm) * QKVS + h * HDIM + lw * 8;
#pragma unroll
            for (int kk = 0; kk < 4; ++kk)
                qa[kk] = *(const bf16x8*)(qp + kk * 32);
        }

        f32x4 acc[8];
#pragma unroll
        for (int d = 0; d < 8; ++d) acc[d] = (f32x4){0.f, 0.f, 0.f, 0.f};
        f32x4 accl = (f32x4){0.f, 0.f, 0.f, 0.f};
        float m = -INFINITY;

#pragma unroll
        for (int it = 0; it < 4; ++it) {
            GLOAD_LDS(ks[it], &Ks[0][(t + it * 512) * 8]);
            ks[it] += 128 * QKVS;
            GLOAD_LDS(vs[it], &Vs[0][(t + it * 512) * 8]);
            vs[it] += 128;
        }
        asm volatile("s_waitcnt vmcnt(0)" ::: "memory");
        __builtin_amdgcn_s_barrier();

#pragma unroll 1
        for (int tile = 0; tile < ntiles; ++tile) {
            const int cur = tile & 1;
            const int kv0 = tile * 128;
            const bool more = (tile + 1 < ntiles);
            if (more) {
                ushort* kd = &Ks[cur ^ 1][0];
                ushort* vd = &Vs[cur ^ 1][0];
#pragma unroll
                for (int it = 0; it < 4; ++it) {
                    GLOAD_LDS(ks[it], kd + (t + it * 512) * 8);
                    ks[it] += 128 * QKVS;
                    GLOAD_LDS(vs[it], vd + (t + it * 512) * 8);
                    vs[it] += 128;
                }
            }

            f32x4 sfT[8];
#pragma unroll
            for (int kvb = 0; kvb < 8; ++kvb) sfT[kvb] = (f32x4){0.f, 0.f, 0.f, 0.f};
            __builtin_amdgcn_s_setprio(1);
#pragma unroll
            for (int kvb = 0; kvb < 8; ++kvb)
#pragma unroll
                for (int kk = 0; kk < 4; ++kk) {
                    bf16x8 kb = *(const bf16x8*)&Ks[cur][(kvb * 16 + lm) * 128 + ((kk * 32 + lw * 8) ^ swz)];
                    sfT[kvb] = __builtin_amdgcn_mfma_f32_16x16x32_bf16(kb, qa[kk], sfT[kvb], 0, 0, 0);
                }
            __builtin_amdgcn_s_setprio(0);

            if (tile == ntiles - 1) {
#pragma unroll
                for (int kvb = 0; kvb < 8; ++kvb)
#pragma unroll
                    for (int r = 0; r < 4; ++r) {
                        int kv = kv0 + kvb * 16 + lw * 4 + r;
                        if (kv > q) sfT[kvb][r] = -INFINITY;
                    }
            }

            float rm = fmaxf(fmaxf(sfT[0][0], sfT[0][1]), fmaxf(sfT[0][2], sfT[0][3]));
#pragma unroll
            for (int kvb = 1; kvb < 8; ++kvb)
                rm = fmaxf(rm, fmaxf(fmaxf(sfT[kvb][0], sfT[kvb][1]),
                                     fmaxf(sfT[kvb][2], sfT[kvb][3])));
            rm = fmaxf(rm, __shfl_xor(rm, 16));
            rm = fmaxf(rm, __shfl_xor(rm, 32));

            bool stable = (rm - m <= THRRAW);
            if (!__all((int)stable)) {
                float mn = fmaxf(m, rm);
                float alpha_l = EXP2F((m - mn) * CEXP);
                m = mn;
                float ar[4];
#pragma unroll
                for (int r = 0; r < 4; ++r)
                    ar[r] = __shfl(alpha_l, (l & 48) | (lw * 4 + r));
#pragma unroll
                for (int d = 0; d < 8; ++d) {
                    acc[d][0] *= ar[0];
                    acc[d][1] *= ar[1];
                    acc[d][2] *= ar[2];
                    acc[d][3] *= ar[3];
                }
                accl[0] *= ar[0];
                accl[1] *= ar[1];
                accl[2] *= ar[2];
                accl[3] *= ar[3];
            }

            bf16x8 pa[4];
            float mC = m * CEXP;
#pragma unroll
            for (int kvb = 0; kvb < 8; ++kvb)
#pragma unroll
                for (int r = 0; r < 4; ++r) {
                    float pv = EXP2F(fmaf(sfT[kvb][r], CEXP, -mC));
                    pa[kvb >> 1][(kvb & 1) * 4 + r] = (short)f2bf(pv);
                }

            __builtin_amdgcn_s_setprio(1);
#pragma unroll
            for (int kks = 0; kks < 4; ++kks) {
                accl = __builtin_amdgcn_mfma_f32_16x16x32_bf16(pa[kks], ones, accl, 0, 0, 0);
#pragma unroll
                for (int dcol = 0; dcol < 8; ++dcol) {
                    bf16x8 vb = *(const bf16x8*)&Vs[cur][(dcol * 16 + lm) * 128 + ((kks * 32 + lw * 8) ^ swz)];
                    acc[dcol] = __builtin_amdgcn_mfma_f32_16x16x32_bf16(pa[kks], vb, acc[dcol], 0, 0, 0);
                }
            }
            __builtin_amdgcn_s_setprio(0);

            if (more) {
                asm volatile("s_waitcnt vmcnt(0)" ::: "memory");
                __builtin_amdgcn_s_barrier();
            }
        }

        float rinv[4];
#pragma unroll
        for (int r = 0; r < 4; ++r) rinv[r] = 1.f / accl[r];
        ushort* cp = Ctx + (size_t)(b * SS + qw) * DD + h * HDIM;
#pragma unroll
        for (int d = 0; d < 8; ++d)
#pragma unroll
            for (int r = 0; r < 4; ++r)
                cp[(size_t)(lw * 4 + r) * DD + d * 16 + lm] = f2bf(acc[d][r] * rinv[r]);
        __builtin_amdgcn_s_barrier();
    }
}

extern "C" void kernel_launch(void* const* d_in, const int* in_sizes, int n_in,
                              void* d_out, int out_size, void* d_ws, size_t ws_size,
                              hipStream_t stream) {
    const float* x  = (const float*)d_in[0];
    const float* Wq = (const float*)d_in[1];
    const float* Wk = (const float*)d_in[2];
    const float* Wv = (const float*)d_in[3];
    const float* Wo = (const float*)d_in[4];
    float* out = (float*)d_out;

    // bf16 workspace (~67 MB)
    ushort* xh    = (ushort*)d_ws;                    // [MS, DD]
    ushort* QKV   = xh + (size_t)MS * DD;             // [MS, QKVS]
    ushort* VTb   = QKV + (size_t)MS * QKVS;          // [BB*DKV, SS]
    ushort* WqkvT = VTb + (size_t)MS * DKV;           // [QKVS, DD]
    ushort* WoT   = WqkvT + (size_t)QKVS * DD;        // [DD, DD]
    ushort* Ch    = xh;                               // ctx bf16 aliases xh

    dim3 blk(256);

    // merged prep: x-cast + all 4 weight transposes in ONE launch
    prep4<<<dim3(DD / 32, DD / 32, 5), blk, 0, stream>>>(x, Wq, Wk, Wv, Wo, xh, WqkvT, WoT);

    // fused QKV GEMM + in-epilogue RoPE + in-epilogue V-transpose to VTb
    gemm_qkv<<<dim3(QKVS / 128, MS / 128), dim3(512), 0, stream>>>(xh, WqkvT, QKV, VTb, MS, QKVS, DD);

    // attention: 256 blocks x 512 threads, kv-tile 128 (round-17/23 verified)
    attn_mfma<<<dim3(256), dim3(512), 0, stream>>>(QKV, VTb, Ch);

    // Wo GEMM: BK=64 dbuf -> 512 blocks = exactly 2/CU (single resident round)
    gemm64<false><<<dim3(DD / 128, MS / 128), dim3(512), 0, stream>>>(Ch, WoT, out, MS, DD, DD);
}

// Round 30
// 177.804 us; speedup vs baseline: 1.0156x; 1.0156x over previous
//
#include <hip/hip_runtime.h>
#include <hip/hip_bf16.h>
#include <math.h>

// Problem constants
#define BB 2
#define SS 2048
#define DD 2048
#define HH 16
#define GG 4
#define HDIM 128
#define DKV (GG * HDIM)      // 512
#define MS (BB * SS)         // 4096 rows
#define QKVS 3072            // fused QKV row stride (2048 Q + 512 K + 512 V)

typedef __attribute__((ext_vector_type(8))) short bf16x8;
typedef __attribute__((ext_vector_type(4))) float f32x4;
typedef __attribute__((ext_vector_type(4))) unsigned int u32x4;

#if __has_builtin(__builtin_amdgcn_exp2f)
#define EXP2F __builtin_amdgcn_exp2f
#else
#define EXP2F exp2f
#endif

__device__ __forceinline__ ushort f2bf(float x) {
    __hip_bfloat16 b = __float2bfloat16(x);
    return *(ushort*)&b;
}
__device__ __forceinline__ float bf2f(ushort u) {
    __hip_bfloat16 b;
    *(ushort*)&b = u;
    return __bfloat162float(b);
}

#define GLOAD_LDS(src, dst)                                                        \
    __builtin_amdgcn_global_load_lds(                                              \
        (const __attribute__((address_space(1))) unsigned int*)(src),              \
        (__attribute__((address_space(3))) unsigned int*)(dst), 16, 0, 0)

#define WAITV(n) asm volatile("s_waitcnt vmcnt(" #n ")" ::: "memory")

// ---- merged prep: z=0 Wq, z=1 Wk, z=2 Wv -> WqkvT; z=3 Wo -> WoT; z=4 x-cast ----
__global__ __launch_bounds__(256) void prep4(const float* __restrict__ x,
                                             const float* __restrict__ Wq,
                                             const float* __restrict__ Wk,
                                             const float* __restrict__ Wv,
                                             const float* __restrict__ Wo,
                                             ushort* __restrict__ xh,
                                             ushort* __restrict__ WqkvT,
                                             ushort* __restrict__ WoT) {
    __shared__ ushort tile[32][33];
    const int z = blockIdx.z;
    if (z == 4) {
        int idx = (blockIdx.y * 64 + blockIdx.x) * 256 + threadIdx.x;
        const float4* p = (const float4*)x + (size_t)idx * 2;
        float4 a = p[0], b = p[1];
        float v[8] = {a.x, a.y, a.z, a.w, b.x, b.y, b.z, b.w};
        ushort r[8];
#pragma unroll
        for (int j = 0; j < 8; ++j) r[j] = f2bf(v[j]);
        *((u32x4*)xh + idx) = *(u32x4*)r;
        return;
    }
    if ((z == 1 || z == 2) && blockIdx.x >= DKV / 32) return;
    const float* W = (z == 0) ? Wq : (z == 1) ? Wk : (z == 2) ? Wv : Wo;
    ushort* WT = (z == 3) ? WoT
                          : WqkvT + ((z == 0) ? (size_t)0
                                              : (z == 1) ? (size_t)DD * DD
                                                         : (size_t)(DD + DKV) * DD);
    const int N = (z == 1 || z == 2) ? DKV : DD;
    const int tx = threadIdx.x & 31, ty = threadIdx.x >> 5;  // 32 x 8
    const int n0 = blockIdx.x * 32, k0 = blockIdx.y * 32;
#pragma unroll
    for (int i = 0; i < 4; ++i)
        tile[ty + i * 8][tx] = f2bf(W[(size_t)(k0 + ty + i * 8) * N + n0 + tx]);
    __syncthreads();
#pragma unroll
    for (int i = 0; i < 4; ++i)
        WT[(size_t)(n0 + ty + i * 8) * DD + k0 + tx] = tile[tx][ty + i * 8];
}

// -------- QKV GEMM + fused RoPE epilogue + fused V-transpose epilogue ---------
// BM=BN=128, BK=32, ring-3, 3/CU. Per-XCD 4x24 slab walked in 4x4 SUPERTILES:
// working set 4 A + 4 B panels = 4 MB (fits per-XCD L2); B-panel reuses are
// consecutive -> each panel fetched ~once (vs ~4x under raster walk).
__global__ __launch_bounds__(512) void gemm_qkv(const ushort* __restrict__ A,
                                                const ushort* __restrict__ BT,
                                                ushort* __restrict__ C,
                                                ushort* __restrict__ VT,
                                                int M, int N, int K) {
    constexpr int ABUF = 128 * 32;
    constexpr int BBUF = 128 * 32;
    constexpr int ROWS = 32;   // rows per wave (4 M-waves)
    constexpr int MFR = 2;     // A fragments per wave
    __shared__ ushort As[3 * ABUF + 3 * BBUF];  // 48 KB, also reused as vt tile
    ushort* Bs = As + 3 * ABUF;
    ushort* vt = As;           // V-epilogue tile [128][140], 17920 <= 24576 ush

    const int t = threadIdx.x;
    const int w = t >> 6, l = t & 63;
    const int lm = l & 15, lw = l >> 4;
    const int wr = w >> 1, wc = w & 1;
    // XCD supertile decode: grid 24x32 = 768; xcd = bid&7 owns a 4(bm)x24(bn)
    // slab; walk it in 4x4 supertiles (sub = c>>4, r = (c>>2)&3, q = c&3).
    const int bid = blockIdx.y * gridDim.x + blockIdx.x;
    const int xcd = bid & 7;
    const int c = bid >> 3;                       // 0..95
    const int sub = c >> 4;                       // 0..5
    const int bm = (xcd * 4 + ((c >> 2) & 3)) * 128;
    const int bn = (sub * 4 + (c & 3)) * 128;

    const int NT = K >> 5;
    const int swzc = (lw ^ ((lm >> 1) & 3)) * 8;

    const int ar0 = t >> 2, ac0 = (t & 3) ^ ((ar0 >> 1) & 3);
    const ushort* a0 = A + (size_t)(bm + ar0) * K + ac0 * 8;
    const ushort* b0 = BT + (size_t)(bn + ar0) * K + ac0 * 8;

    auto STAGE = [&](int slot) {
        GLOAD_LDS(a0, &As[slot * ABUF + t * 8]);
        a0 += 32;
        GLOAD_LDS(b0, &Bs[slot * BBUF + t * 8]);
        b0 += 32;
    };

    // remapped n-fragment columns (rope pairs: n and n+2)
    const int ncol[4] = {wc * 32, wc * 32 + 16, wc * 32 + 64, wc * 32 + 80};

    f32x4 acc[MFR][4];
#pragma unroll
    for (int m = 0; m < MFR; ++m)
#pragma unroll
        for (int n = 0; n < 4; ++n) acc[m][n] = (f32x4){0.f, 0.f, 0.f, 0.f};

    STAGE(0);
    STAGE(1);
    int cs = 0, ps = 2;

#pragma unroll 1
    for (int kt = 0; kt < NT; ++kt) {
        if (kt + 1 < NT) {
            WAITV(2);
        } else {
            WAITV(0);
        }
        __builtin_amdgcn_s_barrier();
        if (kt + 2 < NT) STAGE(ps);

        const ushort* Ab = &As[cs * ABUF];
        const ushort* Bb = &Bs[cs * BBUF];
        bf16x8 bfr[4], af[MFR];
#pragma unroll
        for (int n = 0; n < 4; ++n)
            bfr[n] = *(const bf16x8*)&Bb[(ncol[n] + lm) * 32 + swzc];
#pragma unroll
        for (int i = 0; i < MFR; ++i)
            af[i] = *(const bf16x8*)&Ab[(wr * ROWS + i * 16 + lm) * 32 + swzc];
        __builtin_amdgcn_s_setprio(1);
#pragma unroll
        for (int i = 0; i < MFR; ++i)
#pragma unroll
            for (int n = 0; n < 4; ++n)
                acc[i][n] = __builtin_amdgcn_mfma_f32_16x16x32_bf16(af[i], bfr[n], acc[i][n], 0, 0, 0);
        __builtin_amdgcn_s_setprio(0);

        cs = (cs == 2) ? 0 : cs + 1;
        ps = (ps == 2) ? 0 : ps + 1;
    }

    // epilogue: C/D layout col=lm(+ncol), row=lw*4+reg (verified)
    if (bn < 2560) {
        // Q/K head block: apply rope to fp32 acc (pairs n, n+2), write bf16
#pragma unroll
        for (int n = 0; n < 2; ++n) {
            const int i = wc * 32 + n * 16 + lm;  // position within head, [0,64)
            const float inv = exp2f((float)i * -0.2076205059304601f);  // 10000^(-2i/128)
#pragma unroll
            for (int m = 0; m < MFR; ++m)
#pragma unroll
                for (int r = 0; r < 4; ++r) {
                    int row = bm + wr * ROWS + m * 16 + lw * 4 + r;
                    float ang = (float)(row & (SS - 1)) * inv;
                    float c2, sn;
                    __sincosf(ang, &sn, &c2);
                    float x1 = acc[m][n][r], x2 = acc[m][n + 2][r];
                    size_t base = (size_t)row * QKVS + bn + ncol[n] + lm;
                    C[base] = f2bf(x1 * c2 - x2 * sn);
                    C[base + 64] = f2bf(x2 * c2 + x1 * sn);
                }
        }
    } else {
        // V block: transpose + tau-permute straight to VT via reused LDS.
        asm volatile("s_waitcnt lgkmcnt(0)" ::: "memory");
        __builtin_amdgcn_s_barrier();
#pragma unroll
        for (int m = 0; m < MFR; ++m)
#pragma unroll
            for (int n = 0; n < 4; ++n)
#pragma unroll
                for (int r = 0; r < 4; ++r) {
                    int rl = wr * ROWS + m * 16 + lw * 4 + r;
                    vt[rl * 140 + ncol[n] + lm] = f2bf(acc[m][n][r]);
                }
        __syncthreads();
        const int bb = bm >> 11;          // batch
        const int k0g = bm & 2047;        // kv base within batch
        const int d0 = bn - 2560;         // dkv base
#pragma unroll
        for (int it = 0; it < 4; ++it) {
            int j = it * 4096 + t * 8;
            int dkv = j >> 7;
            int poff = j & 127;
            int kv8 = (poff & 96) + ((poff >> 3) & 3) * 4;  // 32a + 4w'
            ushort vals[8];
#pragma unroll
            for (int r = 0; r < 4; ++r) {
                vals[r] = vt[(kv8 + r) * 140 + dkv];          // m'=0
                vals[4 + r] = vt[(kv8 + 16 + r) * 140 + dkv];  // m'=1
            }
            *(u32x4*)&VT[((size_t)bb * DKV + d0 + dkv) * SS + k0g + poff] = *(u32x4*)vals;
        }
    }
}

// ---------------- bf16 MFMA GEMM v4 (Wo): BM=BN=128, BK=64, dbuf, 2/CU ---------
// Per-XCD 4x16 slab walked in 4x4 supertiles (same locality fix).
template <bool OUT_BF16>
__global__ __launch_bounds__(512) void gemm64(const ushort* __restrict__ A,
                                              const ushort* __restrict__ BT,
                                              void* __restrict__ Cout,
                                              int M, int N, int K) {
    __shared__ ushort As[2][128 * 64];  // 32 KB
    __shared__ ushort Bs[2][128 * 64];  // 32 KB
    const int t = threadIdx.x;
    const int w = t >> 6, l = t & 63;
    const int lm = l & 15, lw = l >> 4;
    const int wr = w >> 1, wc = w & 1;  // 4 M-waves x 2 N-waves
    // XCD supertile decode: grid 16x32 = 512; slab 4(bm)x16(bn); 4x4 supertiles
    const int bid = blockIdx.y * gridDim.x + blockIdx.x;
    const int xcd = bid & 7;
    const int c = bid >> 3;                       // 0..63
    const int sub = c >> 4;                       // 0..3
    const int bm = (xcd * 4 + ((c >> 2) & 3)) * 128;
    const int bn = (sub * 4 + (c & 3)) * 128;
    const int NT = K >> 6;

    const int rowc = t >> 3, cc = t & 7;
    const int xb = (cc ^ (rowc & 7)) * 8;  // (rowc+64)&7 == rowc&7
    const ushort* a0 = A + (size_t)(bm + rowc) * K + xb;
    const ushort* a1 = A + (size_t)(bm + rowc + 64) * K + xb;
    const ushort* b0 = BT + (size_t)(bn + rowc) * K + xb;
    const ushort* b1 = BT + (size_t)(bn + rowc + 64) * K + xb;
    const int d0 = t * 8, d1 = (t + 512) * 8;

    auto STAGE = [&](int s) {
        GLOAD_LDS(a0, &As[s][d0]);
        a0 += 64;
        GLOAD_LDS(a1, &As[s][d1]);
        a1 += 64;
        GLOAD_LDS(b0, &Bs[s][d0]);
        b0 += 64;
        GLOAD_LDS(b1, &Bs[s][d1]);
        b1 += 64;
    };

    f32x4 acc[2][4];
#pragma unroll
    for (int m = 0; m < 2; ++m)
#pragma unroll
        for (int n = 0; n < 4; ++n) acc[m][n] = (f32x4){0.f, 0.f, 0.f, 0.f};

    STAGE(0);
    WAITV(0);
    __builtin_amdgcn_s_barrier();

    int buf = 0;
#pragma unroll 1
    for (int kt = 0; kt < NT; ++kt) {
        const bool more = (kt + 1 < NT);
        if (more) STAGE(buf ^ 1);

        bf16x8 af[2][2], bfr[4][2];
#pragma unroll
        for (int ks = 0; ks < 2; ++ks) {
            const int col = (((ks << 2) | lw) ^ (lm & 7)) * 8;
#pragma unroll
            for (int n = 0; n < 4; ++n)
                bfr[n][ks] = *(const bf16x8*)&Bs[buf][(wc * 64 + n * 16 + lm) * 64 + col];
#pragma unroll
            for (int i = 0; i < 2; ++i)
                af[i][ks] = *(const bf16x8*)&As[buf][(wr * 32 + i * 16 + lm) * 64 + col];
        }
        __builtin_amdgcn_s_setprio(1);
#pragma unroll
        for (int ks = 0; ks < 2; ++ks)
#pragma unroll
            for (int i = 0; i < 2; ++i)
#pragma unroll
                for (int n = 0; n < 4; ++n)
                    acc[i][n] = __builtin_amdgcn_mfma_f32_16x16x32_bf16(af[i][ks], bfr[n][ks], acc[i][n], 0, 0, 0);
        __builtin_amdgcn_s_setprio(0);

        if (more) {
            WAITV(0);
            __builtin_amdgcn_s_barrier();
        }
        buf ^= 1;
    }

#pragma unroll
    for (int m = 0; m < 2; ++m)
#pragma unroll
        for (int n = 0; n < 4; ++n)
#pragma unroll
            for (int r = 0; r < 4; ++r) {
                int row = bm + wr * 32 + m * 16 + lw * 4 + r;
                int col = bn + wc * 64 + n * 16 + lm;
                if (OUT_BF16)
                    ((ushort*)Cout)[(size_t)row * N + col] = f2bf(acc[m][n][r]);
                else
                    ((float*)Cout)[(size_t)row * N + col] = acc[m][n][r];
            }
}

// ---------------- MFMA flash attention v14: kv-tile 128 (round-17/23 verified) --
#define SCL 0.08838834764831845f          // 1/sqrt(128)
#define CEXP 0.1275296340545927f          // SCL * log2(e)
#define THRRAW 90.50966799187809f         // 8 / SCL

__global__ __launch_bounds__(512) void attn_mfma(const ushort* __restrict__ QKV,
                                                 const ushort* __restrict__ VT,
                                                 ushort* __restrict__ Ctx) {
    __shared__ ushort Ks[2][128 * 128];  // 64 KB
    __shared__ ushort Vs[2][128 * 128];  // 64 KB
    const int t = threadIdx.x;           // 0..511
    const int w = t >> 6;                // wave 0..7
    const int l = t & 63;
    const int lm = l & 15, lw = l >> 4;
    const int bid = blockIdx.x;
    const int g = bid & 3;
    const int b = (bid >> 2) & 1;
    const int within = bid >> 3;
    const int xq = within & 7;
    const int h = g * 4 + (within >> 3);
    const int swz = (lm & 7) << 3;

    const ushort* kbase = QKV + (size_t)(b * SS) * QKVS + 2048 + g * HDIM;
    const ushort* vbase = VT + ((size_t)b * DKV + g * HDIM) * SS;

    const short one_bf = (short)0x3F80;
    const bf16x8 ones = {one_bf, one_bf, one_bf, one_bf, one_bf, one_bf, one_bf, one_bf};

    int krr[4], koo[4];
#pragma unroll
    for (int it = 0; it < 4; ++it) {
        int c = t + it * 512;
        krr[it] = c >> 4;
        koo[it] = (c & 15) ^ (krr[it] & 7);
    }

#pragma unroll 1
    for (int phase = 0; phase < 2; ++phase) {
        const int qt = (phase == 0) ? xq : (15 - xq);
        const int q0 = qt * 128;
        const int qw = q0 + w * 16;
        const int q = qw + lm;
        const int ntiles = qt + 1;

        const ushort* ks[4];
        const ushort* vs[4];
#pragma unroll
        for (int it = 0; it < 4; ++it) {
            ks[it] = kbase + (size_t)krr[it] * QKVS + koo[it] * 8;
            vs[it] = vbase + (size_t)krr[it] * SS + koo[it] * 8;
        }

        bf16x8 qa[4];
        {
            const ushort* qp = QKV + (size_t)(b * SS + qw + lm) * QKVS + h * HDIM + lw * 8;
#pragma unroll
            for (int kk = 0; kk < 4; ++kk)
                qa[kk] = *(const bf16x8*)(qp + kk * 32);
        }

        f32x4 acc[8];
#pragma unroll
        for (int d = 0; d < 8; ++d) acc[d] = (f32x4){0.f, 0.f, 0.f, 0.f};
        f32x4 accl = (f32x4){0.f, 0.f, 0.f, 0.f};
        float m = -INFINITY;

#pragma unroll
        for (int it = 0; it < 4; ++it) {
            GLOAD_LDS(ks[it], &Ks[0][(t + it * 512) * 8]);
            ks[it] += 128 * QKVS;
            GLOAD_LDS(vs[it], &Vs[0][(t + it * 512) * 8]);
            vs[it] += 128;
        }
        asm volatile("s_waitcnt vmcnt(0)" ::: "memory");
        __builtin_amdgcn_s_barrier();

#pragma unroll 1
        for (int tile = 0; tile < ntiles; ++tile) {
            const int cur = tile & 1;
            const int kv0 = tile * 128;
            const bool more = (tile + 1 < ntiles);
            if (more) {
                ushort* kd = &Ks[cur ^ 1][0];
                ushort* vd = &Vs[cur ^ 1][0];
#pragma unroll
                for (int it = 0; it < 4; ++it) {
                    GLOAD_LDS(ks[it], kd + (t + it * 512) * 8);
                    ks[it] += 128 * QKVS;
                    GLOAD_LDS(vs[it], vd + (t + it * 512) * 8);
                    vs[it] += 128;
                }
            }

            f32x4 sfT[8];
#pragma unroll
            for (int kvb = 0; kvb < 8; ++kvb) sfT[kvb] = (f32x4){0.f, 0.f, 0.f, 0.f};
            __builtin_amdgcn_s_setprio(1);
#pragma unroll
            for (int kvb = 0; kvb < 8; ++kvb)
#pragma unroll
                for (int kk = 0; kk < 4; ++kk) {
                    bf16x8 kb = *(const bf16x8*)&Ks[cur][(kvb * 16 + lm) * 128 + ((kk * 32 + lw * 8) ^ swz)];
                    sfT[kvb] = __builtin_amdgcn_mfma_f32_16x16x32_bf16(kb, qa[kk], sfT[kvb], 0, 0, 0);
                }
            __builtin_amdgcn_s_setprio(0);

            if (tile == ntiles - 1) {
#pragma unroll
                for (int kvb = 0; kvb < 8; ++kvb)
#pragma unroll
                    for (int r = 0; r < 4; ++r) {
                        int kv = kv0 + kvb * 16 + lw * 4 + r;
                        if (kv > q) sfT[kvb][r] = -INFINITY;
                    }
            }

            float rm = fmaxf(fmaxf(sfT[0][0], sfT[0][1]), fmaxf(sfT[0][2], sfT[0][3]));
#pragma unroll
            for (int kvb = 1; kvb < 8; ++kvb)
                rm = fmaxf(rm, fmaxf(fmaxf(sfT[kvb][0], sfT[kvb][1]),
                                     fmaxf(sfT[kvb][2], sfT[kvb][3])));
            rm = fmaxf(rm, __shfl_xor(rm, 16));
            rm = fmaxf(rm, __shfl_xor(rm, 32));

            bool stable = (rm - m <= THRRAW);
            if (!__all((int)stable)) {
                float mn = fmaxf(m, rm);
                float alpha_l = EXP2F((m - mn) * CEXP);
                m = mn;
                float ar[4];
#pragma unroll
                for (int r = 0; r < 4; ++r)
                    ar[r] = __shfl(alpha_l, (l & 48) | (lw * 4 + r));
#pragma unroll
                for (int d = 0; d < 8; ++d) {
                    acc[d][0] *= ar[0];
                    acc[d][1] *= ar[1];
                    acc[d][2] *= ar[2];
                    acc[d][3] *= ar[3];
                }
                accl[0] *= ar[0];
                accl[1] *= ar[1];
                accl[2] *= ar[2];
                accl[3] *= ar[3];
            }

            bf16x8 pa[4];
            float mC = m * CEXP;
#pragma unroll
            for (int kvb = 0; kvb < 8; ++kvb)
#pragma unroll
                for (int r = 0; r < 4; ++r) {
                    float pv = EXP2F(fmaf(sfT[kvb][r], CEXP, -mC));
                    pa[kvb >> 1][(kvb & 1) * 4 + r] = (short)f2bf(pv);
                }

            __builtin_amdgcn_s_setprio(1);
#pragma unroll
            for (int kks = 0; kks < 4; ++kks) {
                accl = __builtin_amdgcn_mfma_f32_16x16x32_bf16(pa[kks], ones, accl, 0, 0, 0);
#pragma unroll
                for (int dcol = 0; dcol < 8; ++dcol) {
                    bf16x8 vb = *(const bf16x8*)&Vs[cur][(dcol * 16 + lm) * 128 + ((kks * 32 + lw * 8) ^ swz)];
                    acc[dcol] = __builtin_amdgcn_mfma_f32_16x16x32_bf16(pa[kks], vb, acc[dcol], 0, 0, 0);
                }
            }
            __builtin_amdgcn_s_setprio(0);

            if (more) {
                asm volatile("s_waitcnt vmcnt(0)" ::: "memory");
                __builtin_amdgcn_s_barrier();
            }
        }

        float rinv[4];
#pragma unroll
        for (int r = 0; r < 4; ++r) rinv[r] = 1.f / accl[r];
        ushort* cp = Ctx + (size_t)(b * SS + qw) * DD + h * HDIM;
#pragma unroll
        for (int d = 0; d < 8; ++d)
#pragma unroll
            for (int r = 0; r < 4; ++r)
                cp[(size_t)(lw * 4 + r) * DD + d * 16 + lm] = f2bf(acc[d][r] * rinv[r]);
        __builtin_amdgcn_s_barrier();
    }
}

extern "C" void kernel_launch(void* const* d_in, const int* in_sizes, int n_in,
                              void* d_out, int out_size, void* d_ws, size_t ws_size,
                              hipStream_t stream) {
    const float* x  = (const float*)d_in[0];
    const float* Wq = (const float*)d_in[1];
    const float* Wk = (const float*)d_in[2];
    const float* Wv = (const float*)d_in[3];
    const float* Wo = (const float*)d_in[4];
    float* out = (float*)d_out;

    // bf16 workspace (~67 MB)
    ushort* xh    = (ushort*)d_ws;                    // [MS, DD]
    ushort* QKV   = xh + (size_t)MS * DD;             // [MS, QKVS]
    ushort* VTb   = QKV + (size_t)MS * QKVS;          // [BB*DKV, SS]
    ushort* WqkvT = VTb + (size_t)MS * DKV;           // [QKVS, DD]
    ushort* WoT   = WqkvT + (size_t)QKVS * DD;        // [DD, DD]
    ushort* Ch    = xh;                               // ctx bf16 aliases xh

    dim3 blk(256);

    // merged prep: x-cast + all 4 weight transposes in ONE launch
    prep4<<<dim3(DD / 32, DD / 32, 5), blk, 0, stream>>>(x, Wq, Wk, Wv, Wo, xh, WqkvT, WoT);

    // fused QKV GEMM + in-epilogue RoPE + in-epilogue V-transpose to VTb
    gemm_qkv<<<dim3(QKVS / 128, MS / 128), dim3(512), 0, stream>>>(xh, WqkvT, QKV, VTb, MS, QKVS, DD);

    // attention: 256 blocks x 512 threads, kv-tile 128 (round-17/23 verified)
    attn_mfma<<<dim3(256), dim3(512), 0, stream>>>(QKV, VTb, Ch);

    // Wo GEMM: BK=64 dbuf -> 512 blocks = exactly 2/CU (single resident round)
    gemm64<false><<<dim3(DD / 128, MS / 128), dim3(512), 0, stream>>>(Ch, WoT, out, MS, DD, DD);
}

// Round 31
// 177.373 us; speedup vs baseline: 1.0181x; 1.0024x over previous
//
#include <hip/hip_runtime.h>
#include <hip/hip_bf16.h>
#include <math.h>

// Problem constants
#define BB 2
#define SS 2048
#define DD 2048
#define HH 16
#define GG 4
#define HDIM 128
#define DKV (GG * HDIM)      // 512
#define MS (BB * SS)         // 4096 rows
#define QKVS 3072            // fused QKV row stride (2048 Q + 512 K + 512 V)

typedef __attribute__((ext_vector_type(8))) short bf16x8;
typedef __attribute__((ext_vector_type(4))) float f32x4;
typedef __attribute__((ext_vector_type(4))) unsigned int u32x4;

#if __has_builtin(__builtin_amdgcn_exp2f)
#define EXP2F __builtin_amdgcn_exp2f
#else
#define EXP2F exp2f
#endif

__device__ __forceinline__ ushort f2bf(float x) {
    __hip_bfloat16 b = __float2bfloat16(x);
    return *(ushort*)&b;
}
__device__ __forceinline__ float bf2f(ushort u) {
    __hip_bfloat16 b;
    *(ushort*)&b = u;
    return __bfloat162float(b);
}

#define GLOAD_LDS(src, dst)                                                        \
    __builtin_amdgcn_global_load_lds(                                              \
        (const __attribute__((address_space(1))) unsigned int*)(src),              \
        (__attribute__((address_space(3))) unsigned int*)(dst), 16, 0, 0)

#define WAITV(n) asm volatile("s_waitcnt vmcnt(" #n ")" ::: "memory")

// ---- merged prep: z=0 Wq, z=1 Wk, z=2 Wv -> WqkvT; z=3 Wo -> WoT; z=4 x-cast ----
__global__ __launch_bounds__(256) void prep4(const float* __restrict__ x,
                                             const float* __restrict__ Wq,
                                             const float* __restrict__ Wk,
                                             const float* __restrict__ Wv,
                                             const float* __restrict__ Wo,
                                             ushort* __restrict__ xh,
                                             ushort* __restrict__ WqkvT,
                                             ushort* __restrict__ WoT) {
    __shared__ ushort tile[32][33];
    const int z = blockIdx.z;
    if (z == 4) {
        int idx = (blockIdx.y * 64 + blockIdx.x) * 256 + threadIdx.x;
        const float4* p = (const float4*)x + (size_t)idx * 2;
        float4 a = p[0], b = p[1];
        float v[8] = {a.x, a.y, a.z, a.w, b.x, b.y, b.z, b.w};
        ushort r[8];
#pragma unroll
        for (int j = 0; j < 8; ++j) r[j] = f2bf(v[j]);
        *((u32x4*)xh + idx) = *(u32x4*)r;
        return;
    }
    if ((z == 1 || z == 2) && blockIdx.x >= DKV / 32) return;
    const float* W = (z == 0) ? Wq : (z == 1) ? Wk : (z == 2) ? Wv : Wo;
    ushort* WT = (z == 3) ? WoT
                          : WqkvT + ((z == 0) ? (size_t)0
                                              : (z == 1) ? (size_t)DD * DD
                                                         : (size_t)(DD + DKV) * DD);
    const int N = (z == 1 || z == 2) ? DKV : DD;
    const int tx = threadIdx.x & 31, ty = threadIdx.x >> 5;  // 32 x 8
    const int n0 = blockIdx.x * 32, k0 = blockIdx.y * 32;
#pragma unroll
    for (int i = 0; i < 4; ++i)
        tile[ty + i * 8][tx] = f2bf(W[(size_t)(k0 + ty + i * 8) * N + n0 + tx]);
    __syncthreads();
#pragma unroll
    for (int i = 0; i < 4; ++i)
        WT[(size_t)(n0 + ty + i * 8) * DD + k0 + tx] = tile[tx][ty + i * 8];
}

// -------- QKV GEMM + fused RoPE epilogue + fused V-transpose epilogue ---------
// BM=BN=128, BK=32, ring-3, 3/CU. Per-XCD 4x24 slab walked in 4x4 SUPERTILES:
// working set 4 A + 4 B panels = 4 MB (fits per-XCD L2); B-panel reuses are
// consecutive -> each panel fetched ~once (vs ~4x under raster walk).
__global__ __launch_bounds__(512) void gemm_qkv(const ushort* __restrict__ A,
                                                const ushort* __restrict__ BT,
                                                ushort* __restrict__ C,
                                                ushort* __restrict__ VT,
                                                int M, int N, int K) {
    constexpr int ABUF = 128 * 32;
    constexpr int BBUF = 128 * 32;
    constexpr int ROWS = 32;   // rows per wave (4 M-waves)
    constexpr int MFR = 2;     // A fragments per wave
    __shared__ ushort As[3 * ABUF + 3 * BBUF];  // 48 KB, also reused as vt tile
    ushort* Bs = As + 3 * ABUF;
    ushort* vt = As;           // V-epilogue tile [128][140], 17920 <= 24576 ush

    const int t = threadIdx.x;
    const int w = t >> 6, l = t & 63;
    const int lm = l & 15, lw = l >> 4;
    const int wr = w >> 1, wc = w & 1;
    // XCD supertile decode: grid 24x32 = 768; xcd = bid&7 owns a 4(bm)x24(bn)
    // slab; walk it in 4x4 supertiles (sub = c>>4, r = (c>>2)&3, q = c&3).
    const int bid = blockIdx.y * gridDim.x + blockIdx.x;
    const int xcd = bid & 7;
    const int c = bid >> 3;                       // 0..95
    const int sub = c >> 4;                       // 0..5
    const int bm = (xcd * 4 + ((c >> 2) & 3)) * 128;
    const int bn = (sub * 4 + (c & 3)) * 128;

    const int NT = K >> 5;
    const int swzc = (lw ^ ((lm >> 1) & 3)) * 8;

    const int ar0 = t >> 2, ac0 = (t & 3) ^ ((ar0 >> 1) & 3);
    const ushort* a0 = A + (size_t)(bm + ar0) * K + ac0 * 8;
    const ushort* b0 = BT + (size_t)(bn + ar0) * K + ac0 * 8;

    auto STAGE = [&](int slot) {
        GLOAD_LDS(a0, &As[slot * ABUF + t * 8]);
        a0 += 32;
        GLOAD_LDS(b0, &Bs[slot * BBUF + t * 8]);
        b0 += 32;
    };

    // remapped n-fragment columns (rope pairs: n and n+2)
    const int ncol[4] = {wc * 32, wc * 32 + 16, wc * 32 + 64, wc * 32 + 80};

    f32x4 acc[MFR][4];
#pragma unroll
    for (int m = 0; m < MFR; ++m)
#pragma unroll
        for (int n = 0; n < 4; ++n) acc[m][n] = (f32x4){0.f, 0.f, 0.f, 0.f};

    STAGE(0);
    STAGE(1);
    int cs = 0, ps = 2;

#pragma unroll 1
    for (int kt = 0; kt < NT; ++kt) {
        if (kt + 1 < NT) {
            WAITV(2);
        } else {
            WAITV(0);
        }
        __builtin_amdgcn_s_barrier();
        if (kt + 2 < NT) STAGE(ps);

        const ushort* Ab = &As[cs * ABUF];
        const ushort* Bb = &Bs[cs * BBUF];
        bf16x8 bfr[4], af[MFR];
#pragma unroll
        for (int n = 0; n < 4; ++n)
            bfr[n] = *(const bf16x8*)&Bb[(ncol[n] + lm) * 32 + swzc];
#pragma unroll
        for (int i = 0; i < MFR; ++i)
            af[i] = *(const bf16x8*)&Ab[(wr * ROWS + i * 16 + lm) * 32 + swzc];
        __builtin_amdgcn_s_setprio(1);
#pragma unroll
        for (int i = 0; i < MFR; ++i)
#pragma unroll
            for (int n = 0; n < 4; ++n)
                acc[i][n] = __builtin_amdgcn_mfma_f32_16x16x32_bf16(af[i], bfr[n], acc[i][n], 0, 0, 0);
        __builtin_amdgcn_s_setprio(0);

        cs = (cs == 2) ? 0 : cs + 1;
        ps = (ps == 2) ? 0 : ps + 1;
    }

    // epilogue: C/D layout col=lm(+ncol), row=lw*4+reg (verified)
    if (bn < 2560) {
        // Q/K head block: apply rope to fp32 acc (pairs n, n+2), write bf16
#pragma unroll
        for (int n = 0; n < 2; ++n) {
            const int i = wc * 32 + n * 16 + lm;  // position within head, [0,64)
            const float inv = exp2f((float)i * -0.2076205059304601f);  // 10000^(-2i/128)
#pragma unroll
            for (int m = 0; m < MFR; ++m)
#pragma unroll
                for (int r = 0; r < 4; ++r) {
                    int row = bm + wr * ROWS + m * 16 + lw * 4 + r;
                    float ang = (float)(row & (SS - 1)) * inv;
                    float c2, sn;
                    __sincosf(ang, &sn, &c2);
                    float x1 = acc[m][n][r], x2 = acc[m][n + 2][r];
                    size_t base = (size_t)row * QKVS + bn + ncol[n] + lm;
                    C[base] = f2bf(x1 * c2 - x2 * sn);
                    C[base + 64] = f2bf(x2 * c2 + x1 * sn);
                }
        }
    } else {
        // V block: transpose + tau-permute straight to VT via reused LDS.
        asm volatile("s_waitcnt lgkmcnt(0)" ::: "memory");
        __builtin_amdgcn_s_barrier();
#pragma unroll
        for (int m = 0; m < MFR; ++m)
#pragma unroll
            for (int n = 0; n < 4; ++n)
#pragma unroll
                for (int r = 0; r < 4; ++r) {
                    int rl = wr * ROWS + m * 16 + lw * 4 + r;
                    vt[rl * 140 + ncol[n] + lm] = f2bf(acc[m][n][r]);
                }
        __syncthreads();
        const int bb = bm >> 11;          // batch
        const int k0g = bm & 2047;        // kv base within batch
        const int d0 = bn - 2560;         // dkv base
#pragma unroll
        for (int it = 0; it < 4; ++it) {
            int j = it * 4096 + t * 8;
            int dkv = j >> 7;
            int poff = j & 127;
            int kv8 = (poff & 96) + ((poff >> 3) & 3) * 4;  // 32a + 4w'
            ushort vals[8];
#pragma unroll
            for (int r = 0; r < 4; ++r) {
                vals[r] = vt[(kv8 + r) * 140 + dkv];          // m'=0
                vals[4 + r] = vt[(kv8 + 16 + r) * 140 + dkv];  // m'=1
            }
            *(u32x4*)&VT[((size_t)bb * DKV + d0 + dkv) * SS + k0g + poff] = *(u32x4*)vals;
        }
    }
}

// ---------------- bf16 MFMA GEMM v4 (Wo): BM=BN=128, BK=64, dbuf, 2/CU ---------
// Per-XCD 4x16 slab walked in 4x4 supertiles (same locality fix).
template <bool OUT_BF16>
__global__ __launch_bounds__(512) void gemm64(const ushort* __restrict__ A,
                                              const ushort* __restrict__ BT,
                                              void* __restrict__ Cout,
                                              int M, int N, int K) {
    __shared__ ushort As[2][128 * 64];  // 32 KB
    __shared__ ushort Bs[2][128 * 64];  // 32 KB
    const int t = threadIdx.x;
    const int w = t >> 6, l = t & 63;
    const int lm = l & 15, lw = l >> 4;
    const int wr = w >> 1, wc = w & 1;  // 4 M-waves x 2 N-waves
    // XCD supertile decode: grid 16x32 = 512; slab 4(bm)x16(bn); 4x4 supertiles
    const int bid = blockIdx.y * gridDim.x + blockIdx.x;
    const int xcd = bid & 7;
    const int c = bid >> 3;                       // 0..63
    const int sub = c >> 4;                       // 0..3
    const int bm = (xcd * 4 + ((c >> 2) & 3)) * 128;
    const int bn = (sub * 4 + (c & 3)) * 128;
    const int NT = K >> 6;

    const int rowc = t >> 3, cc = t & 7;
    const int xb = (cc ^ (rowc & 7)) * 8;  // (rowc+64)&7 == rowc&7
    const ushort* a0 = A + (size_t)(bm + rowc) * K + xb;
    const ushort* a1 = A + (size_t)(bm + rowc + 64) * K + xb;
    const ushort* b0 = BT + (size_t)(bn + rowc) * K + xb;
    const ushort* b1 = BT + (size_t)(bn + rowc + 64) * K + xb;
    const int d0 = t * 8, d1 = (t + 512) * 8;

    auto STAGE = [&](int s) {
        GLOAD_LDS(a0, &As[s][d0]);
        a0 += 64;
        GLOAD_LDS(a1, &As[s][d1]);
        a1 += 64;
        GLOAD_LDS(b0, &Bs[s][d0]);
        b0 += 64;
        GLOAD_LDS(b1, &Bs[s][d1]);
        b1 += 64;
    };

    f32x4 acc[2][4];
#pragma unroll
    for (int m = 0; m < 2; ++m)
#pragma unroll
        for (int n = 0; n < 4; ++n) acc[m][n] = (f32x4){0.f, 0.f, 0.f, 0.f};

    STAGE(0);
    WAITV(0);
    __builtin_amdgcn_s_barrier();

    int buf = 0;
#pragma unroll 1
    for (int kt = 0; kt < NT; ++kt) {
        const bool more = (kt + 1 < NT);
        if (more) STAGE(buf ^ 1);

        bf16x8 af[2][2], bfr[4][2];
#pragma unroll
        for (int ks = 0; ks < 2; ++ks) {
            const int col = (((ks << 2) | lw) ^ (lm & 7)) * 8;
#pragma unroll
            for (int n = 0; n < 4; ++n)
                bfr[n][ks] = *(const bf16x8*)&Bs[buf][(wc * 64 + n * 16 + lm) * 64 + col];
#pragma unroll
            for (int i = 0; i < 2; ++i)
                af[i][ks] = *(const bf16x8*)&As[buf][(wr * 32 + i * 16 + lm) * 64 + col];
        }
        __builtin_amdgcn_s_setprio(1);
#pragma unroll
        for (int ks = 0; ks < 2; ++ks)
#pragma unroll
            for (int i = 0; i < 2; ++i)
#pragma unroll
                for (int n = 0; n < 4; ++n)
                    acc[i][n] = __builtin_amdgcn_mfma_f32_16x16x32_bf16(af[i][ks], bfr[n][ks], acc[i][n], 0, 0, 0);
        __builtin_amdgcn_s_setprio(0);

        if (more) {
            WAITV(0);
            __builtin_amdgcn_s_barrier();
        }
        buf ^= 1;
    }

#pragma unroll
    for (int m = 0; m < 2; ++m)
#pragma unroll
        for (int n = 0; n < 4; ++n)
#pragma unroll
            for (int r = 0; r < 4; ++r) {
                int row = bm + wr * 32 + m * 16 + lw * 4 + r;
                int col = bn + wc * 64 + n * 16 + lm;
                if (OUT_BF16)
                    ((ushort*)Cout)[(size_t)row * N + col] = f2bf(acc[m][n][r]);
                else
                    ((float*)Cout)[(size_t)row * N + col] = acc[m][n][r];
            }
}

// ---------------- MFMA flash attention v14: kv-tile 128 (round-17/23 verified) --
#define SCL 0.08838834764831845f          // 1/sqrt(128)
#define CEXP 0.1275296340545927f          // SCL * log2(e)
#define THRRAW 90.50966799187809f         // 8 / SCL

__global__ __launch_bounds__(512) void attn_mfma(const ushort* __restrict__ QKV,
                                                 const ushort* __restrict__ VT,
                                                 ushort* __restrict__ Ctx) {
    __shared__ ushort Ks[2][128 * 128];  // 64 KB
    __shared__ ushort Vs[2][128 * 128];  // 64 KB
    const int t = threadIdx.x;           // 0..511
    const int w = t >> 6;                // wave 0..7
    const int l = t & 63;
    const int lm = l & 15, lw = l >> 4;
    const int bid = blockIdx.x;
    const int g = bid & 3;
    const int b = (bid >> 2) & 1;
    const int within = bid >> 3;
    const int xq = within & 7;
    const int h = g * 4 + (within >> 3);
    const int swz = (lm & 7) << 3;

    const ushort* kbase = QKV + (size_t)(b * SS) * QKVS + 2048 + g * HDIM;
    const ushort* vbase = VT + ((size_t)b * DKV + g * HDIM) * SS;

    const short one_bf = (short)0x3F80;
    const bf16x8 ones = {one_bf, one_bf, one_bf, one_bf, one_bf, one_bf, one_bf, one_bf};

    int krr[4], koo[4];
#pragma unroll
    for (int it = 0; it < 4; ++it) {
        int c = t + it * 512;
        krr[it] = c >> 4;
        koo[it] = (c & 15) ^ (krr[it] & 7);
    }

#pragma unroll 1
    for (int phase = 0; phase < 2; ++phase) {
        const int qt = (phase == 0) ? xq : (15 - xq);
        const int q0 = qt * 128;
        const int qw = q0 + w * 16;
        const int q = qw + lm;
        const int ntiles = qt + 1;

        const ushort* ks[4];
        const ushort* vs[4];
#pragma unroll
        for (int it = 0; it < 4; ++it) {
            ks[it] = kbase + (size_t)krr[it] * QKVS + koo[it] * 8;
            vs[it] = vbase + (size_t)krr[it] * SS + koo[it] * 8;
        }

        bf16x8 qa[4];
        {
            const ushort* qp = QKV + (size_t)(b * SS + qw + lm) * QKVS + h * HDIM + lw * 8;
#pragma unroll
            for (int kk = 0; kk < 4; ++kk)
                qa[kk] = *(const bf16x8*)(qp + kk * 32);
        }

        f32x4 acc[8];
#pragma unroll
        for (int d = 0; d < 8; ++d) acc[d] = (f32x4){0.f, 0.f, 0.f, 0.f};
        f32x4 accl = (f32x4){0.f, 0.f, 0.f, 0.f};
        float m = -INFINITY;

#pragma unroll
        for (int it = 0; it < 4; ++it) {
            GLOAD_LDS(ks[it], &Ks[0][(t + it * 512) * 8]);
            ks[it] += 128 * QKVS;
            GLOAD_LDS(vs[it], &Vs[0][(t + it * 512) * 8]);
            vs[it] += 128;
        }
        asm volatile("s_waitcnt vmcnt(0)" ::: "memory");
        __builtin_amdgcn_s_barrier();

#pragma unroll 1
        for (int tile = 0; tile < ntiles; ++tile) {
            const int cur = tile & 1;
            const int kv0 = tile * 128;
            const bool more = (tile + 1 < ntiles);
            if (more) {
                ushort* kd = &Ks[cur ^ 1][0];
                ushort* vd = &Vs[cur ^ 1][0];
#pragma unroll
                for (int it = 0; it < 4; ++it) {
                    GLOAD_LDS(ks[it], kd + (t + it * 512) * 8);
                    ks[it] += 128 * QKVS;
                    GLOAD_LDS(vs[it], vd + (t + it * 512) * 8);
                    vs[it] += 128;
                }
            }

            f32x4 sfT[8];
#pragma unroll
            for (int kvb = 0; kvb < 8; ++kvb) sfT[kvb] = (f32x4){0.f, 0.f, 0.f, 0.f};
            __builtin_amdgcn_s_setprio(1);
#pragma unroll
            for (int kvb = 0; kvb < 8; ++kvb)
#pragma unroll
                for (int kk = 0; kk < 4; ++kk) {
                    bf16x8 kb = *(const bf16x8*)&Ks[cur][(kvb * 16 + lm) * 128 + ((kk * 32 + lw * 8) ^ swz)];
                    sfT[kvb] = __builtin_amdgcn_mfma_f32_16x16x32_bf16(kb, qa[kk], sfT[kvb], 0, 0, 0);
                }
            __builtin_amdgcn_s_setprio(0);

            if (tile == ntiles - 1) {
#pragma unroll
                for (int kvb = 0; kvb < 8; ++kvb)
#pragma unroll
                    for (int r = 0; r < 4; ++r) {
                        int kv = kv0 + kvb * 16 + lw * 4 + r;
                        if (kv > q) sfT[kvb][r] = -INFINITY;
                    }
            }

            float rm = fmaxf(fmaxf(sfT[0][0], sfT[0][1]), fmaxf(sfT[0][2], sfT[0][3]));
#pragma unroll
            for (int kvb = 1; kvb < 8; ++kvb)
                rm = fmaxf(rm, fmaxf(fmaxf(sfT[kvb][0], sfT[kvb][1]),
                                     fmaxf(sfT[kvb][2], sfT[kvb][3])));
            rm = fmaxf(rm, __shfl_xor(rm, 16));
            rm = fmaxf(rm, __shfl_xor(rm, 32));

            bool stable = (rm - m <= THRRAW);
            if (!__all((int)stable)) {
                float mn = fmaxf(m, rm);
                float alpha_l = EXP2F((m - mn) * CEXP);
                m = mn;
                float ar[4];
#pragma unroll
                for (int r = 0; r < 4; ++r)
                    ar[r] = __shfl(alpha_l, (l & 48) | (lw * 4 + r));
#pragma unroll
                for (int d = 0; d < 8; ++d) {
                    acc[d][0] *= ar[0];
                    acc[d][1] *= ar[1];
                    acc[d][2] *= ar[2];
                    acc[d][3] *= ar[3];
                }
                accl[0] *= ar[0];
                accl[1] *= ar[1];
                accl[2] *= ar[2];
                accl[3] *= ar[3];
            }

            bf16x8 pa[4];
            float mC = m * CEXP;
#pragma unroll
            for (int kvb = 0; kvb < 8; ++kvb)
#pragma unroll
                for (int r = 0; r < 4; ++r) {
                    float pv = EXP2F(fmaf(sfT[kvb][r], CEXP, -mC));
                    pa[kvb >> 1][(kvb & 1) * 4 + r] = (short)f2bf(pv);
                }

            __builtin_amdgcn_s_setprio(1);
#pragma unroll
            for (int kks = 0; kks < 4; ++kks) {
                accl = __builtin_amdgcn_mfma_f32_16x16x32_bf16(pa[kks], ones, accl, 0, 0, 0);
#pragma unroll
                for (int dcol = 0; dcol < 8; ++dcol) {
                    bf16x8 vb = *(const bf16x8*)&Vs[cur][(dcol * 16 + lm) * 128 + ((kks * 32 + lw * 8) ^ swz)];
                    acc[dcol] = __builtin_amdgcn_mfma_f32_16x16x32_bf16(pa[kks], vb, acc[dcol], 0, 0, 0);
                }
            }
            __builtin_amdgcn_s_setprio(0);

            if (more) {
                asm volatile("s_waitcnt vmcnt(0)" ::: "memory");
                __builtin_amdgcn_s_barrier();
            }
        }

        float rinv[4];
#pragma unroll
        for (int r = 0; r < 4; ++r) rinv[r] = 1.f / accl[r];
        ushort* cp = Ctx + (size_t)(b * SS + qw) * DD + h * HDIM;
#pragma unroll
        for (int d = 0; d < 8; ++d)
#pragma unroll
            for (int r = 0; r < 4; ++r)
                cp[(size_t)(lw * 4 + r) * DD + d * 16 + lm] = f2bf(acc[d][r] * rinv[r]);
        __builtin_amdgcn_s_barrier();
    }
}

extern "C" void kernel_launch(void* const* d_in, const int* in_sizes, int n_in,
                              void* d_out, int out_size, void* d_ws, size_t ws_size,
                              hipStream_t stream) {
    const float* x  = (const float*)d_in[0];
    const float* Wq = (const float*)d_in[1];
    const float* Wk = (const float*)d_in[2];
    const float* Wv = (const float*)d_in[3];
    const float* Wo = (const float*)d_in[4];
    float* out = (float*)d_out;

    // bf16 workspace (~67 MB)
    ushort* xh    = (ushort*)d_ws;                    // [MS, DD]
    ushort* QKV   = xh + (size_t)MS * DD;             // [MS, QKVS]
    ushort* VTb   = QKV + (size_t)MS * QKVS;          // [BB*DKV, SS]
    ushort* WqkvT = VTb + (size_t)MS * DKV;           // [QKVS, DD]
    ushort* WoT   = WqkvT + (size_t)QKVS * DD;        // [DD, DD]
    ushort* Ch    = xh;                               // ctx bf16 aliases xh

    dim3 blk(256);

    // merged prep: x-cast + all 4 weight transposes in ONE launch
    prep4<<<dim3(DD / 32, DD / 32, 5), blk, 0, stream>>>(x, Wq, Wk, Wv, Wo, xh, WqkvT, WoT);

    // fused QKV GEMM + in-epilogue RoPE + in-epilogue V-transpose to VTb
    gemm_qkv<<<dim3(QKVS / 128, MS / 128), dim3(512), 0, stream>>>(xh, WqkvT, QKV, VTb, MS, QKVS, DD);

    // attention: 256 blocks x 512 threads, kv-tile 128 (round-17/23 verified)
    attn_mfma<<<dim3(256), dim3(512), 0, stream>>>(QKV, VTb, Ch);

    // Wo GEMM: BK=64 dbuf -> 512 blocks = exactly 2/CU (single resident round)
    gemm64<false><<<dim3(DD / 128, MS / 128), dim3(512), 0, stream>>>(Ch, WoT, out, MS, DD, DD);
}